// Round 9
// baseline (511.051 us; speedup 1.0000x reference)
//
#include <hip/hip_runtime.h>

#define NN 50000
#define NE 800000
#define HD 128

typedef short short8 __attribute__((ext_vector_type(8)));
typedef float floatx4 __attribute__((ext_vector_type(4)));

static __device__ __forceinline__ unsigned short f2bf(float f) {
    unsigned int u = __float_as_uint(f);
    unsigned int lsb = (u >> 16) & 1u;
    u += 0x7fffu + lsb;
    return (unsigned short)(u >> 16);
}

// HW packed f32->bf16 (RNE), 2 elems/instr; lo=src0, hi=src1.
static __device__ __forceinline__ short8 pack2(float4 a, float4 b) {
    union { unsigned int u[4]; short8 s; } r;
    asm("v_cvt_pk_bf16_f32 %0, %1, %2" : "=v"(r.u[0]) : "v"(a.x), "v"(a.y));
    asm("v_cvt_pk_bf16_f32 %0, %1, %2" : "=v"(r.u[1]) : "v"(a.z), "v"(a.w));
    asm("v_cvt_pk_bf16_f32 %0, %1, %2" : "=v"(r.u[2]) : "v"(b.x), "v"(b.y));
    asm("v_cvt_pk_bf16_f32 %0, %1, %2" : "=v"(r.u[3]) : "v"(b.z), "v"(b.w));
    return r.s;
}

static __device__ __forceinline__ floatx4 mfma16x16x32(short8 a, short8 b, floatx4 c) {
    asm("v_mfma_f32_16x16x32_bf16 %0, %1, %2, %0" : "+v"(c) : "v"(a), "v"(b));
    return c;
}

// Hazard guards: inline-asm MFMA is invisible to LLVM's GCNHazardRecognizer.
// NOTE: kernels containing these MFMAs are only safe under a VGPR cap that
// exceeds their natural allocation (spill code between MFMAs gets no hazard
// wait-states -> silent corruption, rounds 5/7). msg natural usage = 56 (r8),
// so the (256,8) cap of 64 is now spill-free.
#define NOPGUARD_INIT8(A) asm volatile("s_nop 3" \
  : "+v"(A[0]),"+v"(A[1]),"+v"(A[2]),"+v"(A[3]),"+v"(A[4]),"+v"(A[5]),"+v"(A[6]),"+v"(A[7]))
#define NOPGUARD8(A) asm volatile("s_nop 7\ns_nop 7" \
  : "+v"(A[0]),"+v"(A[1]),"+v"(A[2]),"+v"(A[3]),"+v"(A[4]),"+v"(A[5]),"+v"(A[6]),"+v"(A[7]))

// ---------------- weight packing (unchanged) ----------------
__global__ void pack_weights(const float* __restrict__ mW1, const float* __restrict__ mW2,
                             const float* __restrict__ uW1, const float* __restrict__ uW2,
                             unsigned short* __restrict__ W1p, unsigned short* __restrict__ W2p,
                             unsigned short* __restrict__ U1p, unsigned short* __restrict__ U2p) {
    int t = blockIdx.x * 256 + threadIdx.x;
    const float* src; unsigned short* dst; int kmax; int i;
    if (t < 40960)        { src = mW1; dst = W1p; kmax = 291; i = t; }
    else if (t < 57344)   { src = mW2; dst = W2p; kmax = 128; i = t - 40960; }
    else if (t < 90112)   { src = uW1; dst = U1p; kmax = 256; i = t - 57344; }
    else if (t < 106496)  { src = uW2; dst = U2p; kmax = 128; i = t - 90112; }
    else return;
    int j = i & 7;
    int lane = (i >> 3) & 63;
    int n = (i >> 9) & 7;
    int kk = i >> 12;
    int k = kk * 32 + ((lane >> 4) << 3) + j;
    int c = n * 16 + (lane & 15);
    float v = (k < kmax) ? src[k * 128 + c] : 0.0f;
    dst[i] = f2bf(v);
}

// ---------------- fp32 -> bf16 cast (x and edge_attr at rest) ----------------
__global__ void cast_kernel(const float* __restrict__ in, unsigned short* __restrict__ out,
                            int n8) {
    int t = blockIdx.x * 256 + threadIdx.x;
    if (t < n8) {
        float4 a = *reinterpret_cast<const float4*>(in + (size_t)t * 8);
        float4 b = *reinterpret_cast<const float4*>(in + (size_t)t * 8 + 4);
        *reinterpret_cast<short8*>(out + (size_t)t * 8) = pack2(a, b);
    }
}

// ---------------- CSR build: hist -> scan -> scatter ----------------
__global__ void hist_kernel(const int* __restrict__ ei, int* __restrict__ counts) {
    int e = blockIdx.x * 256 + threadIdx.x;
    if (e < NE) atomicAdd(&counts[ei[NE + e]], 1);
}

__global__ __launch_bounds__(1024)
void scan1_kernel(const int* __restrict__ counts, int* __restrict__ partial,
                  int* __restrict__ bsum) {
    __shared__ int wsum[16];
    int tid = threadIdx.x;
    int gid = blockIdx.x * 1024 + tid;
    int lane = tid & 63, w = tid >> 6;
    int v = (gid < NN) ? counts[gid] : 0;
    int s = v;
    #pragma unroll
    for (int o = 1; o < 64; o <<= 1) { int t = __shfl_up(s, o); if (lane >= o) s += t; }
    if (lane == 63) wsum[w] = s;
    __syncthreads();
    if (w == 0 && lane < 16) {
        int t = wsum[lane];
        #pragma unroll
        for (int o = 1; o < 16; o <<= 1) { int u = __shfl_up(t, o); if (lane >= o) t += u; }
        wsum[lane] = t;
    }
    __syncthreads();
    int base = (w > 0) ? wsum[w - 1] : 0;
    if (gid < NN) partial[gid] = base + s - v;
    if (tid == 1023) bsum[blockIdx.x] = base + s;
}

__global__ void scan2_kernel(int* __restrict__ bsum, int n) {
    int lane = threadIdx.x;
    int v = (lane < n) ? bsum[lane] : 0;
    int s = v;
    #pragma unroll
    for (int o = 1; o < 64; o <<= 1) { int t = __shfl_up(s, o); if (lane >= o) s += t; }
    if (lane < n) bsum[lane] = s - v;
}

// Writes packed (eid | src<<20 | dst<<36) and precomputed rel_coords (bf16x4)
// at the dst-sorted position.
__global__ void scatter_kernel(const int* __restrict__ ei, const int* __restrict__ partial,
                               const int* __restrict__ bsum, int* __restrict__ cursor,
                               const float* __restrict__ cd,
                               unsigned long long* __restrict__ epack,
                               uint2* __restrict__ relb) {
    int e = blockIdx.x * 256 + threadIdx.x;
    if (e < NE) {
        int d = ei[NE + e];
        int s = ei[e];
        int pos = partial[d] + bsum[d >> 10] + atomicAdd(&cursor[d], 1);
        epack[pos] = (unsigned long long)e
                   | ((unsigned long long)s << 20)
                   | ((unsigned long long)d << 36);
        float r0 = cd[d * 3 + 0] - cd[s * 3 + 0];
        float r1 = cd[d * 3 + 1] - cd[s * 3 + 1];
        float r2 = cd[d * 3 + 2] - cd[s * 3 + 2];
        uint2 rr;
        asm("v_cvt_pk_bf16_f32 %0, %1, %2" : "=v"(rr.x) : "v"(r0), "v"(r1));
        asm("v_cvt_pk_bf16_f32 %0, %1, %2" : "=v"(rr.y) : "v"(r2), "v"(0.0f));
        relb[pos] = rr;
    }
}

// ---------------- message MLP: direct bf16 fragment gather + segmented aggregation ----------------
// 64 dst-sorted edges per block, 4 waves. (256,8): natural VGPR=56 (r8) fits
// the 64-reg/8-wave cap with slack -> no spills; probes the occupancy pin.
__global__ __launch_bounds__(256, 8)
void msg_kernel(const unsigned short* __restrict__ xb, const unsigned short* __restrict__ eab,
                const unsigned long long* __restrict__ epack, const uint2* __restrict__ relb,
                const unsigned short* __restrict__ W1p, const float* __restrict__ mb1,
                const unsigned short* __restrict__ W2p, const float* __restrict__ mb2,
                float* __restrict__ aggr) {
    __shared__ unsigned short sH[64 * 136];   // hidden tile, then bf16 out tile
    __shared__ int sDst[64];

    const int tid = threadIdx.x;
    const int lane = tid & 63;
    const int wid = tid >> 6;
    const int g = lane >> 4;
    const int lr = lane & 15;
    const int arow = wid * 16 + lr;          // this lane's edge row in the 64-tile
    const int e0 = blockIdx.x * 64;

    const unsigned long long p = epack[e0 + arow];
    const int eid = (int)(p & 0xFFFFFull);
    const int src = (int)((p >> 20) & 0xFFFFull);
    const int dst = (int)(p >> 36);
    if (g == 0) sDst[arow] = dst;

    // 9 direct short8 gathers + one 8B rel load.
    const unsigned short* xs = xb + (size_t)src * 128 + g * 8;
    const unsigned short* xd = xb + (size_t)dst * 128 + g * 8;
    const unsigned short* ep = eab + (size_t)eid * 32 + g * 8;
    const uint2 rr = relb[e0 + arow];

    short8 af[10];
    #pragma unroll
    for (int kk = 0; kk < 4; ++kk) {
        af[kk]     = *reinterpret_cast<const short8*>(xs + kk * 32);
        af[4 + kk] = *reinterpret_cast<const short8*>(xd + kk * 32);
    }
    af[8] = *reinterpret_cast<const short8*>(ep);
    {   // k 288..295: rel (g==0 lanes only; other g cover zero-padded weights)
        union { unsigned int u[4]; short8 s; } a9;
        a9.u[0] = (g == 0) ? rr.x : 0u;
        a9.u[1] = (g == 0) ? rr.y : 0u;
        a9.u[2] = 0u; a9.u[3] = 0u;
        af[9] = a9.s;
    }

    // Layer 1: (64x320) @ (320x128)
    floatx4 acc[8];
    #pragma unroll
    for (int n = 0; n < 8; ++n)
        #pragma unroll
        for (int r = 0; r < 4; ++r) acc[n][r] = 0.0f;
    NOPGUARD_INIT8(acc);

    #pragma unroll
    for (int kk = 0; kk < 10; ++kk) {
        const short8* wb = reinterpret_cast<const short8*>(W1p) + (kk * 8) * 64 + lane;
        #pragma unroll
        for (int n = 0; n < 8; ++n)
            acc[n] = mfma16x16x32(af[kk], wb[n * 64], acc[n]);
    }
    NOPGUARD8(acc);

    // bias + ReLU -> sH (bf16)
    #pragma unroll
    for (int n = 0; n < 8; ++n) {
        float bias = mb1[n * 16 + lr];
        #pragma unroll
        for (int r = 0; r < 4; ++r) {
            int row = wid * 16 + g * 4 + r;
            sH[row * 136 + n * 16 + lr] = f2bf(fmaxf(acc[n][r] + bias, 0.0f));
        }
    }
    __syncthreads();

    // Pull layer-2 A fragments to registers, then the buffer is free for reuse.
    short8 a2[4];
    #pragma unroll
    for (int kk = 0; kk < 4; ++kk)
        a2[kk] = *reinterpret_cast<const short8*>(&sH[arow * 136 + kk * 32 + g * 8]);
    __syncthreads();

    // Layer 2: (64x128) @ (128x128)
    floatx4 acc2[8];
    #pragma unroll
    for (int n = 0; n < 8; ++n)
        #pragma unroll
        for (int r = 0; r < 4; ++r) acc2[n][r] = 0.0f;
    NOPGUARD_INIT8(acc2);

    #pragma unroll
    for (int kk = 0; kk < 4; ++kk) {
        const short8* wb = reinterpret_cast<const short8*>(W2p) + (kk * 8) * 64 + lane;
        #pragma unroll
        for (int n = 0; n < 8; ++n)
            acc2[n] = mfma16x16x32(a2[kk], wb[n * 64], acc2[n]);
    }
    NOPGUARD8(acc2);

    // bias -> bf16 LDS out tile (same buffer as hidden tile)
    #pragma unroll
    for (int n = 0; n < 8; ++n) {
        float bias = mb2[n * 16 + lr];
        #pragma unroll
        for (int r = 0; r < 4; ++r) {
            int row = wid * 16 + g * 4 + r;
            sH[row * 136 + n * 16 + lr] = f2bf(acc2[n][r] + bias);
        }
    }
    __syncthreads();

    // Segmented reduction over dst-sorted rows: one atomic row per distinct dst.
    {
        int col = tid & 127;
        int half = tid >> 7;
        int row = 0, s = 0;
        while (row < 64) {
            int d = sDst[row];
            int row2 = row + 1;
            while (row2 < 64 && sDst[row2] == d) ++row2;
            if ((s & 1) == half) {
                float sum = 0.0f;
                for (int r = row; r < row2; ++r) {
                    unsigned int uu = sH[r * 136 + col];
                    sum += __uint_as_float(uu << 16);
                }
                atomicAdd(&aggr[d * 128 + col], sum);
            }
            row = row2; ++s;
        }
    }
}

// ---------------- node update MLP + residual + LayerNorm (unchanged) ----------------
__global__ __launch_bounds__(256, 4)
void node_kernel(const unsigned short* __restrict__ xb, const float* __restrict__ x,
                 const float* __restrict__ aggr,
                 const unsigned short* __restrict__ U1p, const float* __restrict__ ub1,
                 const unsigned short* __restrict__ U2p, const float* __restrict__ ub2,
                 const float* __restrict__ gamma, const float* __restrict__ beta,
                 float* __restrict__ out) {
    __shared__ unsigned short sH[64 * 136];

    const int tid = threadIdx.x;
    const int lane = tid & 63;
    const int wid = tid >> 6;
    const int g = lane >> 4;
    const int lr = lane & 15;
    const int arow = wid * 16 + lr;
    const int n0 = blockIdx.x * 64;

    int nd0 = n0 + arow;
    int ndc0 = (nd0 < NN) ? nd0 : (NN - 1);

    const unsigned short* xp = xb + (size_t)ndc0 * 128 + g * 8;
    const float* ap = aggr + (size_t)ndc0 * 128 + g * 8;

    short8 af[8];
    float4 ta[8];
    #pragma unroll
    for (int kk = 0; kk < 4; ++kk) {
        af[kk] = *reinterpret_cast<const short8*>(xp + kk * 32);
        ta[2 * kk]     = *reinterpret_cast<const float4*>(ap + kk * 32);
        ta[2 * kk + 1] = *reinterpret_cast<const float4*>(ap + kk * 32 + 4);
    }
    #pragma unroll
    for (int kk = 0; kk < 4; ++kk)
        af[4 + kk] = pack2(ta[2 * kk], ta[2 * kk + 1]);

    // Layer 1: (64x256) @ (256x128)
    floatx4 acc[8];
    #pragma unroll
    for (int n = 0; n < 8; ++n)
        #pragma unroll
        for (int r = 0; r < 4; ++r) acc[n][r] = 0.0f;
    NOPGUARD_INIT8(acc);

    #pragma unroll
    for (int kk = 0; kk < 8; ++kk) {
        const short8* wb = reinterpret_cast<const short8*>(U1p) + (kk * 8) * 64 + lane;
        #pragma unroll
        for (int n = 0; n < 8; ++n)
            acc[n] = mfma16x16x32(af[kk], wb[n * 64], acc[n]);
    }
    NOPGUARD8(acc);

    #pragma unroll
    for (int n = 0; n < 8; ++n) {
        float bias = ub1[n * 16 + lr];
        #pragma unroll
        for (int r = 0; r < 4; ++r) {
            int row = wid * 16 + g * 4 + r;
            sH[row * 136 + n * 16 + lr] = f2bf(fmaxf(acc[n][r] + bias, 0.0f));
        }
    }
    __syncthreads();

    short8 a2[4];
    #pragma unroll
    for (int kk = 0; kk < 4; ++kk)
        a2[kk] = *reinterpret_cast<const short8*>(&sH[arow * 136 + kk * 32 + g * 8]);

    // Layer 2: (64x128) @ (128x128)
    floatx4 acc2[8];
    #pragma unroll
    for (int n = 0; n < 8; ++n)
        #pragma unroll
        for (int r = 0; r < 4; ++r) acc2[n][r] = 0.0f;
    NOPGUARD_INIT8(acc2);

    #pragma unroll
    for (int kk = 0; kk < 4; ++kk) {
        const short8* wb = reinterpret_cast<const short8*>(U2p) + (kk * 8) * 64 + lane;
        #pragma unroll
        for (int n = 0; n < 8; ++n)
            acc2[n] = mfma16x16x32(a2[kk], wb[n * 64], acc2[n]);
    }
    NOPGUARD8(acc2);

    // Epilogue: residual + LayerNorm in registers (16-lane shfl_xor row-reduce).
    #pragma unroll
    for (int r = 0; r < 4; ++r) {
        int row = wid * 16 + g * 4 + r;
        int nd = n0 + row;
        int ndc = (nd < NN) ? nd : (NN - 1);
        float vals[8];
        float s1 = 0.0f, s2 = 0.0f;
        #pragma unroll
        for (int n = 0; n < 8; ++n) {
            int col = n * 16 + lr;
            float v = acc2[n][r] + ub2[col] + x[ndc * 128 + col];
            vals[n] = v;
            s1 += v;
            s2 += v * v;
        }
        #pragma unroll
        for (int m = 1; m < 16; m <<= 1) {
            s1 += __shfl_xor(s1, m);
            s2 += __shfl_xor(s2, m);
        }
        float mean = s1 * (1.0f / 128.0f);
        float var = s2 * (1.0f / 128.0f) - mean * mean;
        float inv = rsqrtf(var + 1e-5f);
        if (nd < NN) {
            #pragma unroll
            for (int n = 0; n < 8; ++n) {
                int col = n * 16 + lr;
                out[nd * 128 + col] = (vals[n] - mean) * inv * gamma[col] + beta[col];
            }
        }
    }
}

extern "C" void kernel_launch(void* const* d_in, const int* in_sizes, int n_in,
                              void* d_out, int out_size, void* d_ws, size_t ws_size,
                              hipStream_t stream) {
    const float* x     = (const float*)d_in[0];
    const int*   ei    = (const int*)d_in[1];
    const float* ea    = (const float*)d_in[2];
    const float* cd    = (const float*)d_in[3];
    const float* mW1   = (const float*)d_in[4];
    const float* mb1   = (const float*)d_in[5];
    const float* mW2   = (const float*)d_in[6];
    const float* mb2   = (const float*)d_in[7];
    const float* uW1   = (const float*)d_in[8];
    const float* ub1   = (const float*)d_in[9];
    const float* uW2   = (const float*)d_in[10];
    const float* ub2   = (const float*)d_in[11];
    const float* gamma = (const float*)d_in[12];
    const float* beta  = (const float*)d_in[13];
    float* out = (float*)d_out;

    char* ws = (char*)d_ws;
    unsigned short* W1p = (unsigned short*)(ws);                     // 81,920 B
    unsigned short* W2p = (unsigned short*)(ws + 81920);             // 32,768 B
    unsigned short* U1p = (unsigned short*)(ws + 114688);            // 65,536 B
    unsigned short* U2p = (unsigned short*)(ws + 180224);            // 32,768 B
    int* counts  = (int*)(ws + 212992);                              // 200,704 B
    int* partial = (int*)(ws + 413696);                              // 200,704 B
    int* bsum    = (int*)(ws + 614400);                              // 256 B
    int* cursor  = (int*)(ws + 614656);                              // 200,704 B
    unsigned long long* epack = (unsigned long long*)(ws + 815360);  // 6,400,000 B
    uint2* relb  = (uint2*)(ws + 7215360);                           // 6,400,000 B
    unsigned short* xbuf = (unsigned short*)(ws + 13615360);         // 12,800,000 B
    unsigned short* eabuf = (unsigned short*)(ws + 26415360);        // 51,200,000 B
    // total ws use: 77,615,360 B

    float* aggr = out;   // aggr lives in d_out (exactly NN*HD floats)

    hipMemsetAsync(counts, 0, NN * sizeof(int), stream);
    hipMemsetAsync(cursor, 0, NN * sizeof(int), stream);
    hipMemsetAsync(aggr, 0, (size_t)NN * HD * sizeof(float), stream);

    pack_weights<<<416, 256, 0, stream>>>(mW1, mW2, uW1, uW2, W1p, W2p, U1p, U2p);
    cast_kernel<<<(NN * HD / 8 + 255) / 256, 256, 0, stream>>>(x, xbuf, NN * HD / 8);
    cast_kernel<<<(NE * 32 / 8 + 255) / 256, 256, 0, stream>>>(ea, eabuf, NE * 32 / 8);
    hist_kernel<<<(NE + 255) / 256, 256, 0, stream>>>(ei, counts);
    scan1_kernel<<<(NN + 1023) / 1024, 1024, 0, stream>>>(counts, partial, bsum);
    scan2_kernel<<<1, 64, 0, stream>>>(bsum, (NN + 1023) / 1024);
    scatter_kernel<<<(NE + 255) / 256, 256, 0, stream>>>(ei, partial, bsum, cursor, cd, epack, relb);
    msg_kernel<<<NE / 64, 256, 0, stream>>>(xbuf, eabuf, epack, relb, W1p, mb1, W2p, mb2, aggr);
    node_kernel<<<(NN + 63) / 64, 256, 0, stream>>>(xbuf, x, aggr, U1p, ub1, U2p, ub2, gamma, beta, out);
}

// Round 10
// 480.881 us; speedup vs baseline: 1.0627x; 1.0627x over previous
//
#include <hip/hip_runtime.h>

#define NN 50000
#define NE 800000
#define HD 128

typedef short short8 __attribute__((ext_vector_type(8)));
typedef float floatx4 __attribute__((ext_vector_type(4)));

static __device__ __forceinline__ unsigned short f2bf(float f) {
    unsigned int u = __float_as_uint(f);
    unsigned int lsb = (u >> 16) & 1u;
    u += 0x7fffu + lsb;
    return (unsigned short)(u >> 16);
}

// HW packed f32->bf16 (RNE), 2 elems/instr; lo=src0, hi=src1.
static __device__ __forceinline__ short8 pack2(float4 a, float4 b) {
    union { unsigned int u[4]; short8 s; } r;
    asm("v_cvt_pk_bf16_f32 %0, %1, %2" : "=v"(r.u[0]) : "v"(a.x), "v"(a.y));
    asm("v_cvt_pk_bf16_f32 %0, %1, %2" : "=v"(r.u[1]) : "v"(a.z), "v"(a.w));
    asm("v_cvt_pk_bf16_f32 %0, %1, %2" : "=v"(r.u[2]) : "v"(b.x), "v"(b.y));
    asm("v_cvt_pk_bf16_f32 %0, %1, %2" : "=v"(r.u[3]) : "v"(b.z), "v"(b.w));
    return r.s;
}

static __device__ __forceinline__ floatx4 mfma16x16x32(short8 a, short8 b, floatx4 c) {
    asm("v_mfma_f32_16x16x32_bf16 %0, %1, %2, %0" : "+v"(c) : "v"(a), "v"(b));
    return c;
}

// Hazard guards: inline-asm MFMA is invisible to LLVM's GCNHazardRecognizer.
// Register-cap ledger for kernels containing these MFMAs:
//   (256,4) cap 128: natural 56 -> safe (r8: 268us, occ 44%)
//   (256,8) cap  64: allocator squeezed to 32 + scratch -> +360MB writes, SLOW (r9)
//   (256,6) cap  85: natural 56 + slack -> this round's probe
#define NOPGUARD_INIT8(A) asm volatile("s_nop 3" \
  : "+v"(A[0]),"+v"(A[1]),"+v"(A[2]),"+v"(A[3]),"+v"(A[4]),"+v"(A[5]),"+v"(A[6]),"+v"(A[7]))
#define NOPGUARD8(A) asm volatile("s_nop 7\ns_nop 7" \
  : "+v"(A[0]),"+v"(A[1]),"+v"(A[2]),"+v"(A[3]),"+v"(A[4]),"+v"(A[5]),"+v"(A[6]),"+v"(A[7]))

// ---------------- weight packing (unchanged) ----------------
__global__ void pack_weights(const float* __restrict__ mW1, const float* __restrict__ mW2,
                             const float* __restrict__ uW1, const float* __restrict__ uW2,
                             unsigned short* __restrict__ W1p, unsigned short* __restrict__ W2p,
                             unsigned short* __restrict__ U1p, unsigned short* __restrict__ U2p) {
    int t = blockIdx.x * 256 + threadIdx.x;
    const float* src; unsigned short* dst; int kmax; int i;
    if (t < 40960)        { src = mW1; dst = W1p; kmax = 291; i = t; }
    else if (t < 57344)   { src = mW2; dst = W2p; kmax = 128; i = t - 40960; }
    else if (t < 90112)   { src = uW1; dst = U1p; kmax = 256; i = t - 57344; }
    else if (t < 106496)  { src = uW2; dst = U2p; kmax = 128; i = t - 90112; }
    else return;
    int j = i & 7;
    int lane = (i >> 3) & 63;
    int n = (i >> 9) & 7;
    int kk = i >> 12;
    int k = kk * 32 + ((lane >> 4) << 3) + j;
    int c = n * 16 + (lane & 15);
    float v = (k < kmax) ? src[k * 128 + c] : 0.0f;
    dst[i] = f2bf(v);
}

// ---------------- fp32 -> bf16 cast (x at rest) ----------------
__global__ void cast_kernel(const float* __restrict__ in, unsigned short* __restrict__ out,
                            int n8) {
    int t = blockIdx.x * 256 + threadIdx.x;
    if (t < n8) {
        float4 a = *reinterpret_cast<const float4*>(in + (size_t)t * 8);
        float4 b = *reinterpret_cast<const float4*>(in + (size_t)t * 8 + 4);
        *reinterpret_cast<short8*>(out + (size_t)t * 8) = pack2(a, b);
    }
}

// ---------------- CSR build: hist -> scan -> scatter ----------------
__global__ void hist_kernel(const int* __restrict__ ei, int* __restrict__ counts) {
    int e = blockIdx.x * 256 + threadIdx.x;
    if (e < NE) atomicAdd(&counts[ei[NE + e]], 1);
}

__global__ __launch_bounds__(1024)
void scan1_kernel(const int* __restrict__ counts, int* __restrict__ partial,
                  int* __restrict__ bsum) {
    __shared__ int wsum[16];
    int tid = threadIdx.x;
    int gid = blockIdx.x * 1024 + tid;
    int lane = tid & 63, w = tid >> 6;
    int v = (gid < NN) ? counts[gid] : 0;
    int s = v;
    #pragma unroll
    for (int o = 1; o < 64; o <<= 1) { int t = __shfl_up(s, o); if (lane >= o) s += t; }
    if (lane == 63) wsum[w] = s;
    __syncthreads();
    if (w == 0 && lane < 16) {
        int t = wsum[lane];
        #pragma unroll
        for (int o = 1; o < 16; o <<= 1) { int u = __shfl_up(t, o); if (lane >= o) t += u; }
        wsum[lane] = t;
    }
    __syncthreads();
    int base = (w > 0) ? wsum[w - 1] : 0;
    if (gid < NN) partial[gid] = base + s - v;
    if (tid == 1023) bsum[blockIdx.x] = base + s;
}

__global__ void scan2_kernel(int* __restrict__ bsum, int n) {
    int lane = threadIdx.x;
    int v = (lane < n) ? bsum[lane] : 0;
    int s = v;
    #pragma unroll
    for (int o = 1; o < 64; o <<= 1) { int t = __shfl_up(s, o); if (lane >= o) s += t; }
    if (lane < n) bsum[lane] = s - v;
}

// Writes packed (src | dst<<16), precomputed bf16 rel_coords, AND the bf16
// edge_attr row -- all at the dst-sorted position. msg then reads edge data
// fully sequentially; only the two x-rows remain gathered.
__global__ void scatter_kernel(const int* __restrict__ ei, const int* __restrict__ partial,
                               const int* __restrict__ bsum, int* __restrict__ cursor,
                               const float* __restrict__ cd, const float* __restrict__ ea,
                               unsigned int* __restrict__ epack,
                               uint2* __restrict__ relb,
                               unsigned short* __restrict__ eab) {
    int e = blockIdx.x * 256 + threadIdx.x;
    if (e < NE) {
        int d = ei[NE + e];
        int s = ei[e];
        int pos = partial[d] + bsum[d >> 10] + atomicAdd(&cursor[d], 1);
        epack[pos] = (unsigned int)s | ((unsigned int)d << 16);
        float r0 = cd[d * 3 + 0] - cd[s * 3 + 0];
        float r1 = cd[d * 3 + 1] - cd[s * 3 + 1];
        float r2 = cd[d * 3 + 2] - cd[s * 3 + 2];
        uint2 rr;
        asm("v_cvt_pk_bf16_f32 %0, %1, %2" : "=v"(rr.x) : "v"(r0), "v"(r1));
        asm("v_cvt_pk_bf16_f32 %0, %1, %2" : "=v"(rr.y) : "v"(r2), "v"(0.0f));
        relb[pos] = rr;
        const float* eap = ea + (size_t)e * 32;
        unsigned short* eo = eab + (size_t)pos * 32;
        #pragma unroll
        for (int q = 0; q < 4; ++q) {
            float4 a = *reinterpret_cast<const float4*>(eap + q * 8);
            float4 b = *reinterpret_cast<const float4*>(eap + q * 8 + 4);
            *reinterpret_cast<short8*>(eo + q * 8) = pack2(a, b);
        }
    }
}

// ---------------- message MLP: direct bf16 fragment gather + segmented aggregation ----------------
// 64 dst-sorted edges per block, 4 waves, launch_bounds(256,6): cap 85 VGPR
// vs natural 56 -> no allocator squeeze; 6 blocks/CU (LDS 107 KB).
__global__ __launch_bounds__(256, 6)
void msg_kernel(const unsigned short* __restrict__ xb, const unsigned short* __restrict__ eab,
                const unsigned int* __restrict__ epack, const uint2* __restrict__ relb,
                const unsigned short* __restrict__ W1p, const float* __restrict__ mb1,
                const unsigned short* __restrict__ W2p, const float* __restrict__ mb2,
                float* __restrict__ aggr) {
    __shared__ unsigned short sH[64 * 136];   // hidden tile, then bf16 out tile
    __shared__ int sDst[64];

    const int tid = threadIdx.x;
    const int lane = tid & 63;
    const int wid = tid >> 6;
    const int g = lane >> 4;
    const int lr = lane & 15;
    const int arow = wid * 16 + lr;          // this lane's edge row in the 64-tile
    const int e0 = blockIdx.x * 64;

    const unsigned int p = epack[e0 + arow];
    const int src = (int)(p & 0xFFFFu);
    const int dst = (int)(p >> 16);
    if (g == 0) sDst[arow] = dst;

    // 8 x-row gathers + sequential edge-data loads.
    const unsigned short* xs = xb + (size_t)src * 128 + g * 8;
    const unsigned short* xd = xb + (size_t)dst * 128 + g * 8;
    const unsigned short* ep = eab + (size_t)(e0 + arow) * 32 + g * 8;
    const uint2 rr = relb[e0 + arow];

    short8 af[10];
    #pragma unroll
    for (int kk = 0; kk < 4; ++kk) {
        af[kk]     = *reinterpret_cast<const short8*>(xs + kk * 32);
        af[4 + kk] = *reinterpret_cast<const short8*>(xd + kk * 32);
    }
    af[8] = *reinterpret_cast<const short8*>(ep);
    {   // k 288..295: rel (g==0 lanes only; other g cover zero-padded weights)
        union { unsigned int u[4]; short8 s; } a9;
        a9.u[0] = (g == 0) ? rr.x : 0u;
        a9.u[1] = (g == 0) ? rr.y : 0u;
        a9.u[2] = 0u; a9.u[3] = 0u;
        af[9] = a9.s;
    }

    // Layer 1: (64x320) @ (320x128)
    floatx4 acc[8];
    #pragma unroll
    for (int n = 0; n < 8; ++n)
        #pragma unroll
        for (int r = 0; r < 4; ++r) acc[n][r] = 0.0f;
    NOPGUARD_INIT8(acc);

    #pragma unroll
    for (int kk = 0; kk < 10; ++kk) {
        const short8* wb = reinterpret_cast<const short8*>(W1p) + (kk * 8) * 64 + lane;
        #pragma unroll
        for (int n = 0; n < 8; ++n)
            acc[n] = mfma16x16x32(af[kk], wb[n * 64], acc[n]);
    }
    NOPGUARD8(acc);

    // bias + ReLU -> sH (bf16)
    #pragma unroll
    for (int n = 0; n < 8; ++n) {
        float bias = mb1[n * 16 + lr];
        #pragma unroll
        for (int r = 0; r < 4; ++r) {
            int row = wid * 16 + g * 4 + r;
            sH[row * 136 + n * 16 + lr] = f2bf(fmaxf(acc[n][r] + bias, 0.0f));
        }
    }
    __syncthreads();

    // Pull layer-2 A fragments to registers, then the buffer is free for reuse.
    short8 a2[4];
    #pragma unroll
    for (int kk = 0; kk < 4; ++kk)
        a2[kk] = *reinterpret_cast<const short8*>(&sH[arow * 136 + kk * 32 + g * 8]);
    __syncthreads();

    // Layer 2: (64x128) @ (128x128)
    floatx4 acc2[8];
    #pragma unroll
    for (int n = 0; n < 8; ++n)
        #pragma unroll
        for (int r = 0; r < 4; ++r) acc2[n][r] = 0.0f;
    NOPGUARD_INIT8(acc2);

    #pragma unroll
    for (int kk = 0; kk < 4; ++kk) {
        const short8* wb = reinterpret_cast<const short8*>(W2p) + (kk * 8) * 64 + lane;
        #pragma unroll
        for (int n = 0; n < 8; ++n)
            acc2[n] = mfma16x16x32(a2[kk], wb[n * 64], acc2[n]);
    }
    NOPGUARD8(acc2);

    // bias -> bf16 LDS out tile (same buffer as hidden tile)
    #pragma unroll
    for (int n = 0; n < 8; ++n) {
        float bias = mb2[n * 16 + lr];
        #pragma unroll
        for (int r = 0; r < 4; ++r) {
            int row = wid * 16 + g * 4 + r;
            sH[row * 136 + n * 16 + lr] = f2bf(acc2[n][r] + bias);
        }
    }
    __syncthreads();

    // Segmented reduction over dst-sorted rows: one atomic row per distinct dst.
    {
        int col = tid & 127;
        int half = tid >> 7;
        int row = 0, s = 0;
        while (row < 64) {
            int d = sDst[row];
            int row2 = row + 1;
            while (row2 < 64 && sDst[row2] == d) ++row2;
            if ((s & 1) == half) {
                float sum = 0.0f;
                for (int r = row; r < row2; ++r) {
                    unsigned int uu = sH[r * 136 + col];
                    sum += __uint_as_float(uu << 16);
                }
                atomicAdd(&aggr[d * 128 + col], sum);
            }
            row = row2; ++s;
        }
    }
}

// ---------------- node update MLP + residual + LayerNorm (unchanged) ----------------
__global__ __launch_bounds__(256, 4)
void node_kernel(const unsigned short* __restrict__ xb, const float* __restrict__ x,
                 const float* __restrict__ aggr,
                 const unsigned short* __restrict__ U1p, const float* __restrict__ ub1,
                 const unsigned short* __restrict__ U2p, const float* __restrict__ ub2,
                 const float* __restrict__ gamma, const float* __restrict__ beta,
                 float* __restrict__ out) {
    __shared__ unsigned short sH[64 * 136];

    const int tid = threadIdx.x;
    const int lane = tid & 63;
    const int wid = tid >> 6;
    const int g = lane >> 4;
    const int lr = lane & 15;
    const int arow = wid * 16 + lr;
    const int n0 = blockIdx.x * 64;

    int nd0 = n0 + arow;
    int ndc0 = (nd0 < NN) ? nd0 : (NN - 1);

    const unsigned short* xp = xb + (size_t)ndc0 * 128 + g * 8;
    const float* ap = aggr + (size_t)ndc0 * 128 + g * 8;

    short8 af[8];
    float4 ta[8];
    #pragma unroll
    for (int kk = 0; kk < 4; ++kk) {
        af[kk] = *reinterpret_cast<const short8*>(xp + kk * 32);
        ta[2 * kk]     = *reinterpret_cast<const float4*>(ap + kk * 32);
        ta[2 * kk + 1] = *reinterpret_cast<const float4*>(ap + kk * 32 + 4);
    }
    #pragma unroll
    for (int kk = 0; kk < 4; ++kk)
        af[4 + kk] = pack2(ta[2 * kk], ta[2 * kk + 1]);

    // Layer 1: (64x256) @ (256x128)
    floatx4 acc[8];
    #pragma unroll
    for (int n = 0; n < 8; ++n)
        #pragma unroll
        for (int r = 0; r < 4; ++r) acc[n][r] = 0.0f;
    NOPGUARD_INIT8(acc);

    #pragma unroll
    for (int kk = 0; kk < 8; ++kk) {
        const short8* wb = reinterpret_cast<const short8*>(U1p) + (kk * 8) * 64 + lane;
        #pragma unroll
        for (int n = 0; n < 8; ++n)
            acc[n] = mfma16x16x32(af[kk], wb[n * 64], acc[n]);
    }
    NOPGUARD8(acc);

    #pragma unroll
    for (int n = 0; n < 8; ++n) {
        float bias = ub1[n * 16 + lr];
        #pragma unroll
        for (int r = 0; r < 4; ++r) {
            int row = wid * 16 + g * 4 + r;
            sH[row * 136 + n * 16 + lr] = f2bf(fmaxf(acc[n][r] + bias, 0.0f));
        }
    }
    __syncthreads();

    short8 a2[4];
    #pragma unroll
    for (int kk = 0; kk < 4; ++kk)
        a2[kk] = *reinterpret_cast<const short8*>(&sH[arow * 136 + kk * 32 + g * 8]);

    // Layer 2: (64x128) @ (128x128)
    floatx4 acc2[8];
    #pragma unroll
    for (int n = 0; n < 8; ++n)
        #pragma unroll
        for (int r = 0; r < 4; ++r) acc2[n][r] = 0.0f;
    NOPGUARD_INIT8(acc2);

    #pragma unroll
    for (int kk = 0; kk < 4; ++kk) {
        const short8* wb = reinterpret_cast<const short8*>(U2p) + (kk * 8) * 64 + lane;
        #pragma unroll
        for (int n = 0; n < 8; ++n)
            acc2[n] = mfma16x16x32(a2[kk], wb[n * 64], acc2[n]);
    }
    NOPGUARD8(acc2);

    // Epilogue: residual + LayerNorm in registers (16-lane shfl_xor row-reduce).
    #pragma unroll
    for (int r = 0; r < 4; ++r) {
        int row = wid * 16 + g * 4 + r;
        int nd = n0 + row;
        int ndc = (nd < NN) ? nd : (NN - 1);
        float vals[8];
        float s1 = 0.0f, s2 = 0.0f;
        #pragma unroll
        for (int n = 0; n < 8; ++n) {
            int col = n * 16 + lr;
            float v = acc2[n][r] + ub2[col] + x[ndc * 128 + col];
            vals[n] = v;
            s1 += v;
            s2 += v * v;
        }
        #pragma unroll
        for (int m = 1; m < 16; m <<= 1) {
            s1 += __shfl_xor(s1, m);
            s2 += __shfl_xor(s2, m);
        }
        float mean = s1 * (1.0f / 128.0f);
        float var = s2 * (1.0f / 128.0f) - mean * mean;
        float inv = rsqrtf(var + 1e-5f);
        if (nd < NN) {
            #pragma unroll
            for (int n = 0; n < 8; ++n) {
                int col = n * 16 + lr;
                out[nd * 128 + col] = (vals[n] - mean) * inv * gamma[col] + beta[col];
            }
        }
    }
}

extern "C" void kernel_launch(void* const* d_in, const int* in_sizes, int n_in,
                              void* d_out, int out_size, void* d_ws, size_t ws_size,
                              hipStream_t stream) {
    const float* x     = (const float*)d_in[0];
    const int*   ei    = (const int*)d_in[1];
    const float* ea    = (const float*)d_in[2];
    const float* cd    = (const float*)d_in[3];
    const float* mW1   = (const float*)d_in[4];
    const float* mb1   = (const float*)d_in[5];
    const float* mW2   = (const float*)d_in[6];
    const float* mb2   = (const float*)d_in[7];
    const float* uW1   = (const float*)d_in[8];
    const float* ub1   = (const float*)d_in[9];
    const float* uW2   = (const float*)d_in[10];
    const float* ub2   = (const float*)d_in[11];
    const float* gamma = (const float*)d_in[12];
    const float* beta  = (const float*)d_in[13];
    float* out = (float*)d_out;

    char* ws = (char*)d_ws;
    unsigned short* W1p = (unsigned short*)(ws);                     // 81,920 B
    unsigned short* W2p = (unsigned short*)(ws + 81920);             // 32,768 B
    unsigned short* U1p = (unsigned short*)(ws + 114688);            // 65,536 B
    unsigned short* U2p = (unsigned short*)(ws + 180224);            // 32,768 B
    int* counts  = (int*)(ws + 212992);                              // 200,704 B
    int* partial = (int*)(ws + 413696);                              // 200,704 B
    int* bsum    = (int*)(ws + 614400);                              // 256 B
    int* cursor  = (int*)(ws + 614656);                              // 200,704 B
    unsigned int* epack = (unsigned int*)(ws + 815360);              // 3,200,000 B
    uint2* relb  = (uint2*)(ws + 4015360);                           // 6,400,000 B
    unsigned short* xbuf = (unsigned short*)(ws + 10415360);         // 12,800,000 B
    unsigned short* eabuf = (unsigned short*)(ws + 23215360);        // 51,200,000 B
    // total ws use: 74,415,360 B

    float* aggr = out;   // aggr lives in d_out (exactly NN*HD floats)

    hipMemsetAsync(counts, 0, NN * sizeof(int), stream);
    hipMemsetAsync(cursor, 0, NN * sizeof(int), stream);
    hipMemsetAsync(aggr, 0, (size_t)NN * HD * sizeof(float), stream);

    pack_weights<<<416, 256, 0, stream>>>(mW1, mW2, uW1, uW2, W1p, W2p, U1p, U2p);
    cast_kernel<<<(NN * HD / 8 + 255) / 256, 256, 0, stream>>>(x, xbuf, NN * HD / 8);
    hist_kernel<<<(NE + 255) / 256, 256, 0, stream>>>(ei, counts);
    scan1_kernel<<<(NN + 1023) / 1024, 1024, 0, stream>>>(counts, partial, bsum);
    scan2_kernel<<<1, 64, 0, stream>>>(bsum, (NN + 1023) / 1024);
    scatter_kernel<<<(NE + 255) / 256, 256, 0, stream>>>(ei, partial, bsum, cursor, cd, ea, epack, relb, eabuf);
    msg_kernel<<<NE / 64, 256, 0, stream>>>(xbuf, eabuf, epack, relb, W1p, mb1, W2p, mb2, aggr);
    node_kernel<<<(NN + 63) / 64, 256, 0, stream>>>(xbuf, x, aggr, U1p, ub1, U2p, ub2, gamma, beta, out);
}

// Round 11
// 399.994 us; speedup vs baseline: 1.2776x; 1.2022x over previous
//
#include <hip/hip_runtime.h>

#define NN 50000
#define NE 800000
#define HD 128

typedef short short8 __attribute__((ext_vector_type(8)));
typedef float floatx4 __attribute__((ext_vector_type(4)));

static __device__ __forceinline__ unsigned short f2bf(float f) {
    unsigned int u = __float_as_uint(f);
    unsigned int lsb = (u >> 16) & 1u;
    u += 0x7fffu + lsb;
    return (unsigned short)(u >> 16);
}

// HW packed f32->bf16 (RNE), 2 elems/instr; lo=src0, hi=src1.
static __device__ __forceinline__ short8 pack2(float4 a, float4 b) {
    union { unsigned int u[4]; short8 s; } r;
    asm("v_cvt_pk_bf16_f32 %0, %1, %2" : "=v"(r.u[0]) : "v"(a.x), "v"(a.y));
    asm("v_cvt_pk_bf16_f32 %0, %1, %2" : "=v"(r.u[1]) : "v"(a.z), "v"(a.w));
    asm("v_cvt_pk_bf16_f32 %0, %1, %2" : "=v"(r.u[2]) : "v"(b.x), "v"(b.y));
    asm("v_cvt_pk_bf16_f32 %0, %1, %2" : "=v"(r.u[3]) : "v"(b.z), "v"(b.w));
    return r.s;
}

static __device__ __forceinline__ floatx4 mfma16x16x32(short8 a, short8 b, floatx4 c) {
    asm("v_mfma_f32_16x16x32_bf16 %0, %1, %2, %0" : "+v"(c) : "v"(a), "v"(b));
    return c;
}

// Hazard guards: inline-asm MFMA is invisible to LLVM's GCNHazardRecognizer.
// Register-cap ledger (msg_kernel): attr 4 -> 56 VGPR, no scratch, 268us (r8).
// attr 6 -> 40 VGPR + 162MB scratch writes, 310us (r10). attr 8 -> 32 VGPR +
// 360MB scratch, 391us (r9). launch_bounds 2nd arg >4 is permanently closed.
#define NOPGUARD_INIT8(A) asm volatile("s_nop 3" \
  : "+v"(A[0]),"+v"(A[1]),"+v"(A[2]),"+v"(A[3]),"+v"(A[4]),"+v"(A[5]),"+v"(A[6]),"+v"(A[7]))
#define NOPGUARD8(A) asm volatile("s_nop 7\ns_nop 7" \
  : "+v"(A[0]),"+v"(A[1]),"+v"(A[2]),"+v"(A[3]),"+v"(A[4]),"+v"(A[5]),"+v"(A[6]),"+v"(A[7]))

// ---------------- weight packing (unchanged) ----------------
__global__ void pack_weights(const float* __restrict__ mW1, const float* __restrict__ mW2,
                             const float* __restrict__ uW1, const float* __restrict__ uW2,
                             unsigned short* __restrict__ W1p, unsigned short* __restrict__ W2p,
                             unsigned short* __restrict__ U1p, unsigned short* __restrict__ U2p) {
    int t = blockIdx.x * 256 + threadIdx.x;
    const float* src; unsigned short* dst; int kmax; int i;
    if (t < 40960)        { src = mW1; dst = W1p; kmax = 291; i = t; }
    else if (t < 57344)   { src = mW2; dst = W2p; kmax = 128; i = t - 40960; }
    else if (t < 90112)   { src = uW1; dst = U1p; kmax = 256; i = t - 57344; }
    else if (t < 106496)  { src = uW2; dst = U2p; kmax = 128; i = t - 90112; }
    else return;
    int j = i & 7;
    int lane = (i >> 3) & 63;
    int n = (i >> 9) & 7;
    int kk = i >> 12;
    int k = kk * 32 + ((lane >> 4) << 3) + j;
    int c = n * 16 + (lane & 15);
    float v = (k < kmax) ? src[k * 128 + c] : 0.0f;
    dst[i] = f2bf(v);
}

// ---------------- fp32 -> bf16 cast (x at rest) ----------------
__global__ void cast_kernel(const float* __restrict__ in, unsigned short* __restrict__ out,
                            int n8) {
    int t = blockIdx.x * 256 + threadIdx.x;
    if (t < n8) {
        float4 a = *reinterpret_cast<const float4*>(in + (size_t)t * 8);
        float4 b = *reinterpret_cast<const float4*>(in + (size_t)t * 8 + 4);
        *reinterpret_cast<short8*>(out + (size_t)t * 8) = pack2(a, b);
    }
}

// ---------------- CSR build: hist -> scan -> scatter ----------------
__global__ void hist_kernel(const int* __restrict__ ei, int* __restrict__ counts) {
    int e = blockIdx.x * 256 + threadIdx.x;
    if (e < NE) atomicAdd(&counts[ei[NE + e]], 1);
}

__global__ __launch_bounds__(1024)
void scan1_kernel(const int* __restrict__ counts, int* __restrict__ partial,
                  int* __restrict__ bsum) {
    __shared__ int wsum[16];
    int tid = threadIdx.x;
    int gid = blockIdx.x * 1024 + tid;
    int lane = tid & 63, w = tid >> 6;
    int v = (gid < NN) ? counts[gid] : 0;
    int s = v;
    #pragma unroll
    for (int o = 1; o < 64; o <<= 1) { int t = __shfl_up(s, o); if (lane >= o) s += t; }
    if (lane == 63) wsum[w] = s;
    __syncthreads();
    if (w == 0 && lane < 16) {
        int t = wsum[lane];
        #pragma unroll
        for (int o = 1; o < 16; o <<= 1) { int u = __shfl_up(t, o); if (lane >= o) t += u; }
        wsum[lane] = t;
    }
    __syncthreads();
    int base = (w > 0) ? wsum[w - 1] : 0;
    if (gid < NN) partial[gid] = base + s - v;
    if (tid == 1023) bsum[blockIdx.x] = base + s;
}

__global__ void scan2_kernel(int* __restrict__ bsum, int n) {
    int lane = threadIdx.x;
    int v = (lane < n) ? bsum[lane] : 0;
    int s = v;
    #pragma unroll
    for (int o = 1; o < 64; o <<= 1) { int t = __shfl_up(s, o); if (lane >= o) s += t; }
    if (lane < n) bsum[lane] = s - v;
}

// Writes packed (src | dst<<16), precomputed bf16 rel_coords, AND the bf16
// edge_attr row -- all at the dst-sorted position. msg then reads edge data
// fully sequentially; only the two x-rows remain gathered.
__global__ void scatter_kernel(const int* __restrict__ ei, const int* __restrict__ partial,
                               const int* __restrict__ bsum, int* __restrict__ cursor,
                               const float* __restrict__ cd, const float* __restrict__ ea,
                               unsigned int* __restrict__ epack,
                               uint2* __restrict__ relb,
                               unsigned short* __restrict__ eab) {
    int e = blockIdx.x * 256 + threadIdx.x;
    if (e < NE) {
        int d = ei[NE + e];
        int s = ei[e];
        int pos = partial[d] + bsum[d >> 10] + atomicAdd(&cursor[d], 1);
        epack[pos] = (unsigned int)s | ((unsigned int)d << 16);
        float r0 = cd[d * 3 + 0] - cd[s * 3 + 0];
        float r1 = cd[d * 3 + 1] - cd[s * 3 + 1];
        float r2 = cd[d * 3 + 2] - cd[s * 3 + 2];
        uint2 rr;
        asm("v_cvt_pk_bf16_f32 %0, %1, %2" : "=v"(rr.x) : "v"(r0), "v"(r1));
        asm("v_cvt_pk_bf16_f32 %0, %1, %2" : "=v"(rr.y) : "v"(r2), "v"(0.0f));
        relb[pos] = rr;
        const float* eap = ea + (size_t)e * 32;
        unsigned short* eo = eab + (size_t)pos * 32;
        #pragma unroll
        for (int q = 0; q < 4; ++q) {
            float4 a = *reinterpret_cast<const float4*>(eap + q * 8);
            float4 b = *reinterpret_cast<const float4*>(eap + q * 8 + 4);
            *reinterpret_cast<short8*>(eo + q * 8) = pack2(a, b);
        }
    }
}

// ---------------- message MLP: direct bf16 fragment gather + bitmask segmented reduce ----------------
// 64 dst-sorted edges per block, 4 waves, launch_bounds(256,4) (proven safe).
__global__ __launch_bounds__(256, 4)
void msg_kernel(const unsigned short* __restrict__ xb, const unsigned short* __restrict__ eab,
                const unsigned int* __restrict__ epack, const uint2* __restrict__ relb,
                const unsigned short* __restrict__ W1p, const float* __restrict__ mb1,
                const unsigned short* __restrict__ W2p, const float* __restrict__ mb2,
                float* __restrict__ aggr) {
    __shared__ unsigned short sH[64 * 136];   // hidden tile, then bf16 out tile
    __shared__ int sDst[64];
    __shared__ unsigned int headm[2];

    const int tid = threadIdx.x;
    const int lane = tid & 63;
    const int wid = tid >> 6;
    const int g = lane >> 4;
    const int lr = lane & 15;
    const int arow = wid * 16 + lr;          // this lane's edge row in the 64-tile
    const int e0 = blockIdx.x * 64;

    const unsigned int p = epack[e0 + arow];
    const int src = (int)(p & 0xFFFFu);
    const int dst = (int)(p >> 16);
    if (g == 0) sDst[arow] = dst;

    // 8 x-row gathers + sequential edge-data loads.
    const unsigned short* xs = xb + (size_t)src * 128 + g * 8;
    const unsigned short* xd = xb + (size_t)dst * 128 + g * 8;
    const unsigned short* ep = eab + (size_t)(e0 + arow) * 32 + g * 8;
    const uint2 rr = relb[e0 + arow];

    short8 af[10];
    #pragma unroll
    for (int kk = 0; kk < 4; ++kk) {
        af[kk]     = *reinterpret_cast<const short8*>(xs + kk * 32);
        af[4 + kk] = *reinterpret_cast<const short8*>(xd + kk * 32);
    }
    af[8] = *reinterpret_cast<const short8*>(ep);
    {   // k 288..295: rel (g==0 lanes only; other g cover zero-padded weights)
        union { unsigned int u[4]; short8 s; } a9;
        a9.u[0] = (g == 0) ? rr.x : 0u;
        a9.u[1] = (g == 0) ? rr.y : 0u;
        a9.u[2] = 0u; a9.u[3] = 0u;
        af[9] = a9.s;
    }

    // Layer 1: (64x320) @ (320x128)
    floatx4 acc[8];
    #pragma unroll
    for (int n = 0; n < 8; ++n)
        #pragma unroll
        for (int r = 0; r < 4; ++r) acc[n][r] = 0.0f;
    NOPGUARD_INIT8(acc);

    #pragma unroll
    for (int kk = 0; kk < 10; ++kk) {
        const short8* wb = reinterpret_cast<const short8*>(W1p) + (kk * 8) * 64 + lane;
        #pragma unroll
        for (int n = 0; n < 8; ++n)
            acc[n] = mfma16x16x32(af[kk], wb[n * 64], acc[n]);
    }
    NOPGUARD8(acc);

    // Segment-head bitmask: head[r] = (r==0) || sDst[r] != sDst[r-1].
    // Wave 0 computes it while other waves run the bias/ReLU epilogue.
    if (tid < 64) {
        bool head = (tid == 0) || (sDst[tid] != sDst[tid - 1]);
        unsigned long long m = __ballot(head);
        if (tid == 0) { headm[0] = (unsigned int)m; headm[1] = (unsigned int)(m >> 32); }
    }

    // bias + ReLU -> sH (bf16)
    #pragma unroll
    for (int n = 0; n < 8; ++n) {
        float bias = mb1[n * 16 + lr];
        #pragma unroll
        for (int r = 0; r < 4; ++r) {
            int row = wid * 16 + g * 4 + r;
            sH[row * 136 + n * 16 + lr] = f2bf(fmaxf(acc[n][r] + bias, 0.0f));
        }
    }
    __syncthreads();

    // Pull layer-2 A fragments to registers, then the buffer is free for reuse.
    short8 a2[4];
    #pragma unroll
    for (int kk = 0; kk < 4; ++kk)
        a2[kk] = *reinterpret_cast<const short8*>(&sH[arow * 136 + kk * 32 + g * 8]);
    __syncthreads();

    // Layer 2: (64x128) @ (128x128)
    floatx4 acc2[8];
    #pragma unroll
    for (int n = 0; n < 8; ++n)
        #pragma unroll
        for (int r = 0; r < 4; ++r) acc2[n][r] = 0.0f;
    NOPGUARD_INIT8(acc2);

    #pragma unroll
    for (int kk = 0; kk < 4; ++kk) {
        const short8* wb = reinterpret_cast<const short8*>(W2p) + (kk * 8) * 64 + lane;
        #pragma unroll
        for (int n = 0; n < 8; ++n)
            acc2[n] = mfma16x16x32(a2[kk], wb[n * 64], acc2[n]);
    }
    NOPGUARD8(acc2);

    // bias -> bf16 LDS out tile (same buffer as hidden tile)
    #pragma unroll
    for (int n = 0; n < 8; ++n) {
        float bias = mb2[n * 16 + lr];
        #pragma unroll
        for (int r = 0; r < 4; ++r) {
            int row = wid * 16 + g * 4 + r;
            sH[row * 136 + n * 16 + lr] = f2bf(acc2[n][r] + bias);
        }
    }
    __syncthreads();

    // Bitmask-driven segmented reduction: segment boundaries from the head
    // mask via register-only bit ops (no serial dependent LDS scan); inner
    // sums are independent pipelined LDS reads. One atomic row per segment.
    {
        const unsigned long long hm =
            ((unsigned long long)headm[1] << 32) | (unsigned long long)headm[0];
        const int col = tid & 127;
        const int half = tid >> 7;
        unsigned long long m = hm;
        int sidx = 0;
        while (m) {
            int start = __ffsll((long long)m) - 1;
            unsigned long long m2 = m & (m - 1);
            int end = m2 ? (__ffsll((long long)m2) - 1) : 64;
            if ((sidx & 1) == half) {
                float sum = 0.0f;
                for (int r = start; r < end; ++r) {
                    unsigned int uu = sH[r * 136 + col];
                    sum += __uint_as_float(uu << 16);
                }
                atomicAdd(&aggr[sDst[start] * 128 + col], sum);
            }
            m = m2; ++sidx;
        }
    }
}

// ---------------- node update MLP + residual + LayerNorm (unchanged) ----------------
__global__ __launch_bounds__(256, 4)
void node_kernel(const unsigned short* __restrict__ xb, const float* __restrict__ x,
                 const float* __restrict__ aggr,
                 const unsigned short* __restrict__ U1p, const float* __restrict__ ub1,
                 const unsigned short* __restrict__ U2p, const float* __restrict__ ub2,
                 const float* __restrict__ gamma, const float* __restrict__ beta,
                 float* __restrict__ out) {
    __shared__ unsigned short sH[64 * 136];

    const int tid = threadIdx.x;
    const int lane = tid & 63;
    const int wid = tid >> 6;
    const int g = lane >> 4;
    const int lr = lane & 15;
    const int arow = wid * 16 + lr;
    const int n0 = blockIdx.x * 64;

    int nd0 = n0 + arow;
    int ndc0 = (nd0 < NN) ? nd0 : (NN - 1);

    const unsigned short* xp = xb + (size_t)ndc0 * 128 + g * 8;
    const float* ap = aggr + (size_t)ndc0 * 128 + g * 8;

    short8 af[8];
    float4 ta[8];
    #pragma unroll
    for (int kk = 0; kk < 4; ++kk) {
        af[kk] = *reinterpret_cast<const short8*>(xp + kk * 32);
        ta[2 * kk]     = *reinterpret_cast<const float4*>(ap + kk * 32);
        ta[2 * kk + 1] = *reinterpret_cast<const float4*>(ap + kk * 32 + 4);
    }
    #pragma unroll
    for (int kk = 0; kk < 4; ++kk)
        af[4 + kk] = pack2(ta[2 * kk], ta[2 * kk + 1]);

    // Layer 1: (64x256) @ (256x128)
    floatx4 acc[8];
    #pragma unroll
    for (int n = 0; n < 8; ++n)
        #pragma unroll
        for (int r = 0; r < 4; ++r) acc[n][r] = 0.0f;
    NOPGUARD_INIT8(acc);

    #pragma unroll
    for (int kk = 0; kk < 8; ++kk) {
        const short8* wb = reinterpret_cast<const short8*>(U1p) + (kk * 8) * 64 + lane;
        #pragma unroll
        for (int n = 0; n < 8; ++n)
            acc[n] = mfma16x16x32(af[kk], wb[n * 64], acc[n]);
    }
    NOPGUARD8(acc);

    #pragma unroll
    for (int n = 0; n < 8; ++n) {
        float bias = ub1[n * 16 + lr];
        #pragma unroll
        for (int r = 0; r < 4; ++r) {
            int row = wid * 16 + g * 4 + r;
            sH[row * 136 + n * 16 + lr] = f2bf(fmaxf(acc[n][r] + bias, 0.0f));
        }
    }
    __syncthreads();

    short8 a2[4];
    #pragma unroll
    for (int kk = 0; kk < 4; ++kk)
        a2[kk] = *reinterpret_cast<const short8*>(&sH[arow * 136 + kk * 32 + g * 8]);

    // Layer 2: (64x128) @ (128x128)
    floatx4 acc2[8];
    #pragma unroll
    for (int n = 0; n < 8; ++n)
        #pragma unroll
        for (int r = 0; r < 4; ++r) acc2[n][r] = 0.0f;
    NOPGUARD_INIT8(acc2);

    #pragma unroll
    for (int kk = 0; kk < 4; ++kk) {
        const short8* wb = reinterpret_cast<const short8*>(U2p) + (kk * 8) * 64 + lane;
        #pragma unroll
        for (int n = 0; n < 8; ++n)
            acc2[n] = mfma16x16x32(a2[kk], wb[n * 64], acc2[n]);
    }
    NOPGUARD8(acc2);

    // Epilogue: residual + LayerNorm in registers (16-lane shfl_xor row-reduce).
    #pragma unroll
    for (int r = 0; r < 4; ++r) {
        int row = wid * 16 + g * 4 + r;
        int nd = n0 + row;
        int ndc = (nd < NN) ? nd : (NN - 1);
        float vals[8];
        float s1 = 0.0f, s2 = 0.0f;
        #pragma unroll
        for (int n = 0; n < 8; ++n) {
            int col = n * 16 + lr;
            float v = acc2[n][r] + ub2[col] + x[ndc * 128 + col];
            vals[n] = v;
            s1 += v;
            s2 += v * v;
        }
        #pragma unroll
        for (int m = 1; m < 16; m <<= 1) {
            s1 += __shfl_xor(s1, m);
            s2 += __shfl_xor(s2, m);
        }
        float mean = s1 * (1.0f / 128.0f);
        float var = s2 * (1.0f / 128.0f) - mean * mean;
        float inv = rsqrtf(var + 1e-5f);
        if (nd < NN) {
            #pragma unroll
            for (int n = 0; n < 8; ++n) {
                int col = n * 16 + lr;
                out[nd * 128 + col] = (vals[n] - mean) * inv * gamma[col] + beta[col];
            }
        }
    }
}

extern "C" void kernel_launch(void* const* d_in, const int* in_sizes, int n_in,
                              void* d_out, int out_size, void* d_ws, size_t ws_size,
                              hipStream_t stream) {
    const float* x     = (const float*)d_in[0];
    const int*   ei    = (const int*)d_in[1];
    const float* ea    = (const float*)d_in[2];
    const float* cd    = (const float*)d_in[3];
    const float* mW1   = (const float*)d_in[4];
    const float* mb1   = (const float*)d_in[5];
    const float* mW2   = (const float*)d_in[6];
    const float* mb2   = (const float*)d_in[7];
    const float* uW1   = (const float*)d_in[8];
    const float* ub1   = (const float*)d_in[9];
    const float* uW2   = (const float*)d_in[10];
    const float* ub2   = (const float*)d_in[11];
    const float* gamma = (const float*)d_in[12];
    const float* beta  = (const float*)d_in[13];
    float* out = (float*)d_out;

    char* ws = (char*)d_ws;
    unsigned short* W1p = (unsigned short*)(ws);                     // 81,920 B
    unsigned short* W2p = (unsigned short*)(ws + 81920);             // 32,768 B
    unsigned short* U1p = (unsigned short*)(ws + 114688);            // 65,536 B
    unsigned short* U2p = (unsigned short*)(ws + 180224);            // 32,768 B
    int* counts  = (int*)(ws + 212992);                              // 200,704 B
    int* cursor  = (int*)(ws + 413696);                              // 200,704 B (adjacent to counts: one memset)
    int* partial = (int*)(ws + 614400);                              // 200,704 B
    int* bsum    = (int*)(ws + 815104);                              // 256 B
    unsigned int* epack = (unsigned int*)(ws + 815360);              // 3,200,000 B
    uint2* relb  = (uint2*)(ws + 4015360);                           // 6,400,000 B
    unsigned short* xbuf = (unsigned short*)(ws + 10415360);         // 12,800,000 B
    unsigned short* eabuf = (unsigned short*)(ws + 23215360);        // 51,200,000 B
    // total ws use: 74,415,360 B

    float* aggr = out;   // aggr lives in d_out (exactly NN*HD floats)

    hipMemsetAsync(counts, 0, 2 * NN * sizeof(int) + (413696 - 212992 - NN * sizeof(int)), stream);
    hipMemsetAsync(aggr, 0, (size_t)NN * HD * sizeof(float), stream);

    pack_weights<<<416, 256, 0, stream>>>(mW1, mW2, uW1, uW2, W1p, W2p, U1p, U2p);
    cast_kernel<<<(NN * HD / 8 + 255) / 256, 256, 0, stream>>>(x, xbuf, NN * HD / 8);
    hist_kernel<<<(NE + 255) / 256, 256, 0, stream>>>(ei, counts);
    scan1_kernel<<<(NN + 1023) / 1024, 1024, 0, stream>>>(counts, partial, bsum);
    scan2_kernel<<<1, 64, 0, stream>>>(bsum, (NN + 1023) / 1024);
    scatter_kernel<<<(NE + 255) / 256, 256, 0, stream>>>(ei, partial, bsum, cursor, cd, ea, epack, relb, eabuf);
    msg_kernel<<<NE / 64, 256, 0, stream>>>(xbuf, eabuf, epack, relb, W1p, mb1, W2p, mb2, aggr);
    node_kernel<<<(NN + 63) / 64, 256, 0, stream>>>(xbuf, x, aggr, U1p, ub1, U2p, ub2, gamma, beta, out);
}